// Round 10
// baseline (4015.517 us; speedup 1.0000x reference)
//
#include <hip/hip_runtime.h>
#include <stdint.h>

#define NN 4096
#define BB 4
#define MROWS 16        // output rows per block
#define TPB 1024        // 16 waves

typedef __attribute__((ext_vector_type(8))) short bf16x8;   // 8 bf16 (4 VGPRs)
typedef __attribute__((ext_vector_type(4))) float f32x4;    // MFMA C/D

// ---------- bf16 round-to-nearest-even ----------
__device__ __forceinline__ uint32_t bf16rne(float f) {
  uint32_t u = __float_as_uint(f);
  return (u + 0x7FFFu + ((u >> 16) & 1u)) >> 16;
}

// ---------- pack B fp32 -> two row-major bf16 planes (32 MB each) ----------
__global__ void pack_planes(const float* __restrict__ Br, const float* __restrict__ Bi,
                            uint4* __restrict__ Brb, uint4* __restrict__ Bib) {
  int i = blockIdx.x * blockDim.x + threadIdx.x;     // over N*N/8
  const float4* r4 = reinterpret_cast<const float4*>(Br) + (size_t)i * 2;
  const float4* m4 = reinterpret_cast<const float4*>(Bi) + (size_t)i * 2;
  float4 a0 = r4[0], a1 = r4[1];
  float4 b0 = m4[0], b1 = m4[1];
  uint4 o;
  o.x = bf16rne(a0.x) | (bf16rne(a0.y) << 16);
  o.y = bf16rne(a0.z) | (bf16rne(a0.w) << 16);
  o.z = bf16rne(a1.x) | (bf16rne(a1.y) << 16);
  o.w = bf16rne(a1.z) | (bf16rne(a1.w) << 16);
  Brb[i] = o;
  o.x = bf16rne(b0.x) | (bf16rne(b0.y) << 16);
  o.y = bf16rne(b0.z) | (bf16rne(b0.w) << 16);
  o.z = bf16rne(b1.x) | (bf16rne(b1.y) << 16);
  o.w = bf16rne(b1.z) | (bf16rne(b1.w) << 16);
  Bib[i] = o;
}

// ---------- x0 = exp(i*theta): state (complex interleaved) + out real plane t=0 ----------
__global__ void init_kernel(const float* __restrict__ ang,
                            float2* __restrict__ st0, float* __restrict__ out0) {
  int i = blockIdx.x * blockDim.x + threadIdx.x;
  if (i < BB * NN) {
    float s, c;
    sincosf(ang[i], &s, &c);
    st0[i] = make_float2(c, s);
    out0[i] = c;
  }
}

// ============================================================================
// MFMA step kernel.
// D[m][c] (m: 16 rows/block, c: 8 valid cols = 4 batches x re/im):
//   pass1: Br . X1, X1[n][2b]=xr_b[n], X1[n][2b+1]=xi_b[n]   (planes 0..7)
//   pass2: Bi . X2, X2[n][2b]=-xi_b[n], X2[n][2b+1]=xr_b[n]  (= plane c^1, neg if c even)
// X LDS layout: chunk-interleaved uint4 slots: slot(nc,p) = nc*8 + ((p + rot(nc)) & 7),
//   rot(nc) = (nc + (nc>>1)) & 7   (nc = node>>3, p = plane 0..7; 16B per slot)
// Fragment layouts (gfx950 16x16x32 bf16):
//   A: lane l holds A[row=l&15][k = (l>>4)*8 + j], j=0..7
//   B: lane l holds B[k = (l>>4)*8 + j][col=l&15]
//   C/D: lane l holds D[row=(l>>4)*4 + i][col=l&15], i=0..3
// ============================================================================
__global__ __launch_bounds__(TPB)
void step_mfma(const uint16_t* __restrict__ Brb,
               const uint16_t* __restrict__ Bib,
               const float* __restrict__ omega,
               const float2* __restrict__ stPrev,
               float2* __restrict__ stNext,
               float* __restrict__ outRe) {
  extern __shared__ char smem[];
  char*  XB  = smem;                         // 512 chunks * 8 planes * 16 B = 64 KB
  float* red = (float*)(smem + 65536);       // 16 waves * 256 fp32 = 16 KB

  const int tid = threadIdx.x;

  // ---- build X planes (bf16) from fp32 state ----
  {
    int b  = tid >> 8;                       // batch 0..3
    int n0 = (tid & 255) * 16;               // 16 nodes
    const float2* sp = stPrev + b * NN + n0;
    float2 v[16];
#pragma unroll
    for (int j = 0; j < 16; ++j) v[j] = sp[j];
    uint32_t xr[8], xi[8];
#pragma unroll
    for (int j = 0; j < 8; ++j) {
      xr[j] = bf16rne(v[2 * j].x) | (bf16rne(v[2 * j + 1].x) << 16);
      xi[j] = bf16rne(v[2 * j].y) | (bf16rne(v[2 * j + 1].y) << 16);
    }
    uint4* Xq = (uint4*)XB;
    int nc0 = n0 >> 3;
    // chunk nc0 (nodes n0..n0+7)
    {
      int rot = (nc0 + (nc0 >> 1)) & 7;
      Xq[nc0 * 8 + ((2 * b     + rot) & 7)] = make_uint4(xr[0], xr[1], xr[2], xr[3]);
      Xq[nc0 * 8 + ((2 * b + 1 + rot) & 7)] = make_uint4(xi[0], xi[1], xi[2], xi[3]);
    }
    // chunk nc0+1 (nodes n0+8..n0+15)
    {
      int nc1 = nc0 + 1;
      int rot = (nc1 + (nc1 >> 1)) & 7;
      Xq[nc1 * 8 + ((2 * b     + rot) & 7)] = make_uint4(xr[4], xr[5], xr[6], xr[7]);
      Xq[nc1 * 8 + ((2 * b + 1 + rot) & 7)] = make_uint4(xi[4], xi[5], xi[6], xi[7]);
    }
  }
  __syncthreads();

  // ---- MFMA main loop ----
  const int w    = tid >> 6;       // k-slice 0..15 (256 nodes each)
  const int lane = tid & 63;
  const int al   = lane & 15;      // A row-local / C col
  const int kq   = lane >> 4;      // k quadrant 0..3
  const int row0 = blockIdx.x * MROWS;

  const int p1 = al & 7;           // pass-1 plane
  const int p2 = p1 ^ 1;           // pass-2 plane
  const uint32_t sm = (al & 1) ? 0u : 0x80008000u;   // negate -xi for even cols

  const uint16_t* arow = Brb + (size_t)(row0 + al) * NN;
  const uint16_t* brow = Bib + (size_t)(row0 + al) * NN;

  f32x4 accA = {0.f, 0.f, 0.f, 0.f};
  f32x4 accB = {0.f, 0.f, 0.f, 0.f};

#pragma unroll
  for (int s = 0; s < 8; ++s) {
    const int k0 = w * 256 + s * 32;
    const int nq = (k0 >> 3) + kq;                 // node-chunk for this lane
    const int rot = (nq + (nq >> 1)) & 7;
    const int koff = k0 + kq * 8;

    bf16x8 a1 = *reinterpret_cast<const bf16x8*>(arow + koff);
    bf16x8 x1 = *reinterpret_cast<const bf16x8*>(XB + (size_t)(nq * 8 + ((p1 + rot) & 7)) * 16);
    accA = __builtin_amdgcn_mfma_f32_16x16x32_bf16(a1, x1, accA, 0, 0, 0);

    bf16x8 a2 = *reinterpret_cast<const bf16x8*>(brow + koff);
    uint4 u2 = *reinterpret_cast<const uint4*>(XB + (size_t)(nq * 8 + ((p2 + rot) & 7)) * 16);
    u2.x ^= sm; u2.y ^= sm; u2.z ^= sm; u2.w ^= sm;
    bf16x8 x2 = __builtin_bit_cast(bf16x8, u2);
    accB = __builtin_amdgcn_mfma_f32_16x16x32_bf16(a2, x2, accB, 0, 0, 0);
  }

  // ---- partial 16x16 tile -> LDS ----
  {
    float* rw = red + w * 256;
#pragma unroll
    for (int i = 0; i < 4; ++i)
      rw[(kq * 4 + i) * 16 + al] = accA[i] + accB[i];
  }
  __syncthreads();

  // ---- cross-wave sum + diagonal + writes ----
  if (tid < 128) {
    int r = tid >> 3;                // row-local 0..15
    int c = tid & 7;                 // col 0..7
    float s = 0.f;
#pragma unroll
    for (int w2 = 0; w2 < 16; ++w2) s += red[w2 * 256 + r * 16 + c];
    int m  = row0 + r;
    int b  = c >> 1;
    int ri = c & 1;
    float om = omega[b * NN + m];
    float2 xv = stPrev[b * NN + m];
    // i*omega*(xr + i*xi) = -omega*xi + i*omega*xr
    s += ri ? (om * xv.x) : (-om * xv.y);
    reinterpret_cast<float*>(stNext)[(b * NN + m) * 2 + ri] = s;
    if (ri == 0) outRe[b * NN + m] = s;     // d_out = REAL plane [t][b][n]
  }
}

// ============================================================================
// Fallback (fp32 B direct, round-4 structure) — only if ws too small to pack.
// ============================================================================
__global__ __launch_bounds__(TPB)
void step_fb(const float* __restrict__ Brf, const float* __restrict__ Bif,
             const float* __restrict__ omega,
             const float2* __restrict__ stPrev, float2* __restrict__ stNext,
             float* __restrict__ outRe) {
  extern __shared__ float lds[];
  float* xl  = lds;
  float* xh  = lds + NN * 4;
  float* red = lds + NN * 8;
  const int tid = threadIdx.x;
#pragma unroll
  for (int k = 0; k < 8; ++k) {
    int idx = tid + k * TPB;
    int half = idx >> 12;
    int n = idx & (NN - 1);
    float2 v0 = stPrev[(half * 2) * NN + n];
    float2 v1 = stPrev[(half * 2 + 1) * NN + n];
    reinterpret_cast<float4*>(half ? xh : xl)[n] = make_float4(v0.x, v0.y, v1.x, v1.y);
  }
  __syncthreads();
  const int w = tid >> 6, lane = tid & 63, rg = w >> 2, q = w & 3;
  const int row0 = blockIdx.x * MROWS + rg * 4;
  float acc[4][8];
#pragma unroll
  for (int r = 0; r < 4; ++r)
#pragma unroll
    for (int c = 0; c < 8; ++c) acc[r][c] = 0.0f;
#define CFMA(A, BR, BI, XA, XB)                                   \
  A[0] = fmaf(BR, XA.x, A[0]); A[0] = fmaf(-BI, XA.y, A[0]);      \
  A[1] = fmaf(BR, XA.y, A[1]); A[1] = fmaf(BI, XA.x, A[1]);       \
  A[2] = fmaf(BR, XA.z, A[2]); A[2] = fmaf(-BI, XA.w, A[2]);      \
  A[3] = fmaf(BR, XA.w, A[3]); A[3] = fmaf(BI, XA.z, A[3]);       \
  A[4] = fmaf(BR, XB.x, A[4]); A[4] = fmaf(-BI, XB.y, A[4]);      \
  A[5] = fmaf(BR, XB.y, A[5]); A[5] = fmaf(BI, XB.x, A[5]);       \
  A[6] = fmaf(BR, XB.z, A[6]); A[6] = fmaf(-BI, XB.w, A[6]);      \
  A[7] = fmaf(BR, XB.w, A[7]); A[7] = fmaf(BI, XB.z, A[7]);
  for (int i4 = 0; i4 < 4; ++i4) {
    const int n0 = q * 1024 + i4 * 256 + lane * 4;
    float4 xa[4], xb[4];
#pragma unroll
    for (int j = 0; j < 4; ++j) {
      xa[j] = reinterpret_cast<const float4*>(xl)[n0 + j];
      xb[j] = reinterpret_cast<const float4*>(xh)[n0 + j];
    }
#pragma unroll
    for (int r = 0; r < 4; ++r) {
      const float4 pvr = reinterpret_cast<const float4*>(Brf + (size_t)(row0 + r) * NN)[q * 256 + i4 * 64 + lane];
      const float4 pvi = reinterpret_cast<const float4*>(Bif + (size_t)(row0 + r) * NN)[q * 256 + i4 * 64 + lane];
      float* a = acc[r];
      CFMA(a, pvr.x, pvi.x, xa[0], xb[0]);
      CFMA(a, pvr.y, pvi.y, xa[1], xb[1]);
      CFMA(a, pvr.z, pvi.z, xa[2], xb[2]);
      CFMA(a, pvr.w, pvi.w, xa[3], xb[3]);
    }
  }
#undef CFMA
  float t0 = acc[0][0], t1 = acc[0][1], t2 = acc[0][2], t3 = acc[0][3];
  float t4 = acc[0][4], t5 = acc[0][5], t6 = acc[0][6], t7 = acc[0][7];
  float t8 = acc[1][0], t9 = acc[1][1], t10 = acc[1][2], t11 = acc[1][3];
  float t12 = acc[1][4], t13 = acc[1][5], t14 = acc[1][6], t15 = acc[1][7];
  float t16 = acc[2][0], t17 = acc[2][1], t18 = acc[2][2], t19 = acc[2][3];
  float t20 = acc[2][4], t21 = acc[2][5], t22 = acc[2][6], t23 = acc[2][7];
  float t24 = acc[3][0], t25 = acc[3][1], t26 = acc[3][2], t27 = acc[3][3];
  float t28 = acc[3][4], t29 = acc[3][5], t30 = acc[3][6], t31 = acc[3][7];
#define RSTEP(LO, HI, M)                                          \
  { float s_ = up ? LO : HI;                                      \
    s_ = __shfl_xor(s_, M, 64);                                   \
    LO = (up ? HI : LO) + s_; }
  { const bool up = (lane & 32) != 0;
    RSTEP(t0, t16, 32)  RSTEP(t1, t17, 32)  RSTEP(t2, t18, 32)  RSTEP(t3, t19, 32)
    RSTEP(t4, t20, 32)  RSTEP(t5, t21, 32)  RSTEP(t6, t22, 32)  RSTEP(t7, t23, 32)
    RSTEP(t8, t24, 32)  RSTEP(t9, t25, 32)  RSTEP(t10, t26, 32) RSTEP(t11, t27, 32)
    RSTEP(t12, t28, 32) RSTEP(t13, t29, 32) RSTEP(t14, t30, 32) RSTEP(t15, t31, 32) }
  { const bool up = (lane & 16) != 0;
    RSTEP(t0, t8, 16)  RSTEP(t1, t9, 16)  RSTEP(t2, t10, 16) RSTEP(t3, t11, 16)
    RSTEP(t4, t12, 16) RSTEP(t5, t13, 16) RSTEP(t6, t14, 16) RSTEP(t7, t15, 16) }
  { const bool up = (lane & 8) != 0;
    RSTEP(t0, t4, 8) RSTEP(t1, t5, 8) RSTEP(t2, t6, 8) RSTEP(t3, t7, 8) }
  { const bool up = (lane & 4) != 0;
    RSTEP(t0, t2, 4) RSTEP(t1, t3, 4) }
  { const bool up = (lane & 2) != 0;
    RSTEP(t0, t1, 2) }
#undef RSTEP
  t0 += __shfl_xor(t0, 1, 64);
  if (!(lane & 1)) red[w * 32 + ((lane >> 1) & 31)] = t0;
  __syncthreads();
  if (tid < 128) {
    int rg2 = tid >> 5, v = tid & 31;
    float s = red[(rg2 * 4 + 0) * 32 + v] + red[(rg2 * 4 + 1) * 32 + v] +
              red[(rg2 * 4 + 2) * 32 + v] + red[(rg2 * 4 + 3) * 32 + v];
    int r = v >> 3, c = v & 7, b = c >> 1, ri = c & 1;
    int m = blockIdx.x * MROWS + rg2 * 4 + r;
    float om = omega[b * NN + m];
    const float* xs = (b < 2) ? xl : xh;
    float xr = xs[m * 4 + (b & 1) * 2];
    float xi = xs[m * 4 + (b & 1) * 2 + 1];
    s += (ri == 0) ? (-om * xi) : (om * xr);
    reinterpret_cast<float*>(stNext)[(b * NN + m) * 2 + ri] = s;
    if (ri == 0) outRe[b * NN + m] = s;
  }
}

// ---------- host ----------
extern "C" void kernel_launch(void* const* d_in, const int* in_sizes, int n_in,
                              void* d_out, int out_size, void* d_ws, size_t ws_size,
                              hipStream_t stream) {
  const float* B_real = (const float*)d_in[0];
  const float* B_imag = (const float*)d_in[1];
  const float* omega  = (const float*)d_in[2];
  const float* ang    = (const float*)d_in[3];
  float* out = (float*)d_out;

  const int NT = out_size / (BB * NN);                          // 256
  const size_t planeBytes = (size_t)NN * NN * 2;                // 32 MB bf16 plane
  const size_t stBytes    = (size_t)2 * BB * NN * sizeof(float2); // 256 KB
  const bool packed = ws_size >= 2 * planeBytes + stBytes;

  uint16_t* Brb = (uint16_t*)d_ws;
  uint16_t* Bib = Brb + (size_t)NN * NN;
  float2* st = packed ? (float2*)((char*)d_ws + 2 * planeBytes)
                      : (float2*)d_ws;
  float2* st0 = st;
  float2* st1 = st + BB * NN;

  const size_t shmemM = 65536 + 16384;                          // 80 KB
  const size_t shmemF = (size_t)(NN * 8 + 16 * 32) * sizeof(float);
  (void)hipFuncSetAttribute((const void*)&step_mfma,
                            hipFuncAttributeMaxDynamicSharedMemorySize, (int)shmemM);
  (void)hipFuncSetAttribute((const void*)&step_fb,
                            hipFuncAttributeMaxDynamicSharedMemorySize, (int)shmemF);

  if (packed) {
    pack_planes<<<NN * NN / 8 / 256, 256, 0, stream>>>(B_real, B_imag,
                                                       (uint4*)Brb, (uint4*)Bib);
  }
  init_kernel<<<(BB * NN + 255) / 256, 256, 0, stream>>>(ang, st0, out);

  for (int t = 1; t < NT; ++t) {
    float2* sp = ((t - 1) & 1) ? st1 : st0;
    float2* sn = (t & 1) ? st1 : st0;
    float* outT = out + (size_t)t * BB * NN;
    if (packed) {
      step_mfma<<<NN / MROWS, TPB, shmemM, stream>>>(Brb, Bib, omega, sp, sn, outT);
    } else {
      step_fb<<<NN / MROWS, TPB, shmemF, stream>>>(B_real, B_imag, omega, sp, sn, outT);
    }
  }
}